// Round 5
// baseline (181.462 us; speedup 1.0000x reference)
//
#include <hip/hip_runtime.h>

// F=32 fields, B=8192 batch, D=64.
// out[b, r*64+c] = s[b,r]*s[b,c], s[b,d] = sum_f in[f,b,0,d].
// Memory-bound: 64 MiB read + 128 MiB write -> ~32-37 us floor (mixed R/W).
//
// ONE SAMPLE PER WAVE (4x the waves of the prior version: 2048 blocks,
// 32 waves/CU -> full occupancy for latency hiding).
//   lane = fq*16 + dv   (fq = field-quarter 0..3, dv = float4 chunk of D)
//   Stage 1: each lane sums 8 fields (f = j*4+fq); per load instruction the
//            wave covers 4x 256B segments -- fully coalesced.
//   Reduce:  __shfl_xor 16/32 -> EVERY lane holds the full s4[dv]; the
//            column vector sc stays in registers (no LDS read).
//   Stage 2: row scalar s[it*4+fq] via wave-local LDS broadcast; stores are
//            1 KiB contiguous per instruction, nontemporal (streaming 128 MiB).

#define NF 32
#define NB 8192
#define ND 64

typedef float f4 __attribute__((ext_vector_type(4)));  // native vec for nontemporal builtins

__global__ __launch_bounds__(256) void opnn_outer_kernel(
    const float* __restrict__ in, float* __restrict__ out) {
    const int tid  = threadIdx.x;
    const int w    = tid >> 6;        // wave in block: 0..3
    const int lane = tid & 63;
    const int fq   = lane >> 4;       // field-quarter 0..3
    const int dv   = lane & 15;       // float4 index within D
    const int b    = blockIdx.x * 4 + w;  // one sample per wave

    // ---- Stage 1: per-lane partial field sum (8 fields each) ----
    const f4* __restrict__ in4 = (const f4*)in;
    const size_t base = (size_t)b * (ND / 4) + dv;
    f4 acc = __builtin_nontemporal_load(&in4[base + (size_t)fq * NB * (ND / 4)]);
    #pragma unroll
    for (int j = 1; j < 8; ++j) {
        const int f = j * 4 + fq;
        acc += __builtin_nontemporal_load(&in4[base + (size_t)f * NB * (ND / 4)]);
    }

    // ---- Cross-lane reduce over the 4 fq groups: xor 16, then xor 32 ----
    #pragma unroll
    for (int m = 16; m <= 32; m <<= 1) {
        acc.x += __shfl_xor(acc.x, m, 64);
        acc.y += __shfl_xor(acc.y, m, 64);
        acc.z += __shfl_xor(acc.z, m, 64);
        acc.w += __shfl_xor(acc.w, m, 64);
    }
    // every lane now holds s4[dv] = full field-sum for its dv chunk

    __shared__ f4 sh[4][16];          // [wave][dv] -- wave-private row vector
    if (fq == 0) sh[w][dv] = acc;
    __builtin_amdgcn_wave_barrier();  // wave-local RAW; compiler emits lgkmcnt wait

    // ---- Stage 2: outer product; sc in registers, sr via LDS broadcast ----
    const float* shf = (const float*)&sh[w][0];
    f4* __restrict__ outp = (f4*)(out + (size_t)b * (ND * ND));
    const f4 sc = acc;                // column vector, already in registers
    #pragma unroll
    for (int it = 0; it < 16; ++it) {
        const float sr = shf[it * 4 + fq];   // row scalar, 4 addrs -> broadcast
        __builtin_nontemporal_store(sr * sc, &outp[it * 64 + lane]);
    }
}

extern "C" void kernel_launch(void* const* d_in, const int* in_sizes, int n_in,
                              void* d_out, int out_size, void* d_ws, size_t ws_size,
                              hipStream_t stream) {
    const float* in = (const float*)d_in[0];
    float* out = (float*)d_out;
    opnn_outer_kernel<<<NB / 4, 256, 0, stream>>>(in, out);
}

// Round 6
// 174.864 us; speedup vs baseline: 1.0377x; 1.0377x over previous
//
#include <hip/hip_runtime.h>

// F=32 fields, B=8192 batch, D=64.
// out[b, r*64+c] = s[b,r]*s[b,c], s[b,d] = sum_f in[f,b,0,d].
// Memory-bound: 64 MiB read + 128 MiB write -> ~32-37 us floor (mixed R/W).
//
// BEST-MEASURED STRUCTURE (R3, 174.1 us total-bench): 1 wave owns 4 samples,
// 16 samples/block, 512 blocks. Measured A/B: removing the barrier = neutral
// (+2.5 us), 1-sample/wave @ full occupancy = regression (+7 us) -> store
// stream saturates at 8 waves/CU; keep the simple form.
//   lane = lb*16 + dv  (lb = sample-in-wave, dv = float4 chunk of D)
//   Stage 1: per-lane field sum, 1 KiB contiguous per wave-load, no reduction.
//   Stage 2: sc hoisted per sample; sr via LDS broadcast; 1 KiB contiguous
//            nontemporal stores (streaming 128 MiB, keep out of L2).

#define NF 32
#define NB 8192
#define ND 64

typedef float f4 __attribute__((ext_vector_type(4)));  // native vec for nontemporal builtins

__global__ __launch_bounds__(256) void opnn_outer_kernel(
    const float* __restrict__ in, float* __restrict__ out) {
    const int tid  = threadIdx.x;
    const int w    = tid >> 6;        // wave in block: 0..3
    const int lane = tid & 63;
    const int lb   = lane >> 4;       // sample within wave: 0..3
    const int dv   = lane & 15;       // float4 index within D
    const int s_local = w * 4 + lb;   // sample within block: 0..15
    const int b = blockIdx.x * 16 + s_local;

    // ---- Stage 1: per-lane field sum (no cross-lane reduction) ----
    const f4* __restrict__ in4 = (const f4*)in;
    const size_t base = (size_t)b * (ND / 4) + dv;
    f4 acc = __builtin_nontemporal_load(&in4[base]);
    #pragma unroll
    for (int f = 1; f < NF; ++f)
        acc += __builtin_nontemporal_load(&in4[base + (size_t)f * NB * (ND / 4)]);

    __shared__ f4 sh[16][16];         // [sample-in-block][dv]
    sh[s_local][dv] = acc;
    __syncthreads();

    // ---- Stage 2: outer product, 1 KiB contiguous per store instruction ----
    const float* shf = (const float*)sh;
    #pragma unroll
    for (int ss = 0; ss < 4; ++ss) {
        const int sidx = w * 4 + ss;                       // sample within block
        const f4 sc = sh[sidx][dv];                        // column vec, hoisted
        f4* __restrict__ outp =
            (f4*)(out + ((size_t)blockIdx.x * 16 + sidx) * (ND * ND));
        #pragma unroll
        for (int it = 0; it < 16; ++it) {
            const float sr = shf[sidx * 64 + it * 4 + lb]; // 4 addrs, 16x broadcast
            __builtin_nontemporal_store(sr * sc, &outp[it * 64 + lane]);
        }
    }
}

extern "C" void kernel_launch(void* const* d_in, const int* in_sizes, int n_in,
                              void* d_out, int out_size, void* d_ws, size_t ws_size,
                              hipStream_t stream) {
    const float* in = (const float*)d_in[0];
    float* out = (float*)d_out;
    opnn_outer_kernel<<<NB / 16, 256, 0, stream>>>(in, out);
}